// Round 1
// 189.157 us; speedup vs baseline: 1.0907x; 1.0907x over previous
//
#include <hip/hip_runtime.h>
#include <hip/hip_bf16.h>

#define BATCH 16
#define NH    8
#define CH    8
#define HH    56
#define WW    56
#define POS   3136          // 56*56 = 49*64
#define QKVC  192
#define OC    64
#define SCALE 0.17677669529663687f   // 32^-0.5

typedef unsigned short ushort_t;
typedef __attribute__((ext_vector_type(8))) short bf16x8;   // 8 bf16 = 4 VGPRs
typedef __attribute__((ext_vector_type(4))) float f32x4;

__device__ __forceinline__ unsigned short f2b(float f) {
    __hip_bfloat16 h = __float2bfloat16(f);
    union { __hip_bfloat16 h; unsigned short u; } c; c.h = h; return c.u;
}
__device__ __forceinline__ unsigned int pk(float lo, float hi) {
    return (unsigned int)f2b(lo) | ((unsigned int)f2b(hi) << 16);
}
__device__ __forceinline__ float bu2f(ushort_t u) {
    union { unsigned int v; float f; } c; c.v = ((unsigned int)u) << 16; return c.f;
}
// async 16B global->LDS (lane-linear dest within wave)
__device__ __forceinline__ void gll16(const ushort_t* g, ushort_t* l) {
    __builtin_amdgcn_global_load_lds((const __attribute__((address_space(1))) void*)g,
                                     (__attribute__((address_space(3))) void*)l, 16, 0, 0);
}

// ---------------------------------------------------------------------------
// prep_x: x[b][c][pos] fp32 -> xT[b][pos][c] bf16 (canonical, no swizzle).
// 64c x 64p tile via LDS. grid (49, 4, 16), 256 thr.
// ---------------------------------------------------------------------------
__global__ __launch_bounds__(256) void prep_x(const float* __restrict__ x,
                                              ushort_t* __restrict__ xT) {
    __shared__ float ld[64][65];
    const int tid = threadIdx.x;
    const int p0 = blockIdx.x * 64, c0 = blockIdx.y * 64, b = blockIdx.z;
    const float* xb = x + ((size_t)b * 256 + c0) * POS + p0;
    #pragma unroll
    for (int it = 0; it < 4; ++it) {
        int idx = it * 256 + tid;
        int c = idx >> 4, pc = (idx & 15) << 2;
        float4 v = *(const float4*)(xb + (size_t)c * POS + pc);
        ld[c][pc] = v.x; ld[c][pc+1] = v.y; ld[c][pc+2] = v.z; ld[c][pc+3] = v.w;
    }
    __syncthreads();
    ushort_t* xo = xT + ((size_t)(b * POS + p0)) * 256 + c0;
    #pragma unroll
    for (int it = 0; it < 2; ++it) {
        int idx = it * 256 + tid;
        int p = idx >> 3, q = (idx & 7) * 8;
        uint4 st = { pk(ld[q][p],   ld[q+1][p]), pk(ld[q+2][p], ld[q+3][p]),
                     pk(ld[q+4][p], ld[q+5][p]), pk(ld[q+6][p], ld[q+7][p]) };
        *(uint4*)(xo + (size_t)p * 256 + q) = st;
    }
}

// ---------------------------------------------------------------------------
// prep_w: qkv_w (192x256) + proj_w (256x64) fp32 -> bf16, PLUS fused attn
// weight tensor wattn[h][ch][ka][12] = {w0..w8, db+rpb, db, 0}.
// grid(67), 256 thr. Blocks 0-63: weight conversion; 64-66: wattn build.
// ---------------------------------------------------------------------------
__global__ __launch_bounds__(256) void prep_w(const float* __restrict__ wq,
                                              const float* __restrict__ wp,
                                              const float* __restrict__ dc_b,
                                              const float* __restrict__ dc1_w,
                                              const float* __restrict__ dc1_b,
                                              const float* __restrict__ rpb,
                                              ushort_t* __restrict__ wq16,
                                              ushort_t* __restrict__ wp16,
                                              float* __restrict__ wattn) {
    int idx = blockIdx.x * 256 + threadIdx.x;   // 16384 float4 units + 768 wattn slots
    if (idx >= 16384) {
        int t = idx - 16384;                    // 0..767, need 576 = 8h * 72(ch*9+ka)
        if (t < 576) {
            int h = t / 72, r = t - h * 72;     // r = ch*9 + ka
            int ka = r % 9;
            float db = dc_b[r] + dc1_b[r];
            float* w = wattn + t * 12;          // t == (h*8+ch)*9 + ka
            #pragma unroll
            for (int j = 0; j < 9; ++j) w[j] = dc1_w[r * 9 + j];
            w[9]  = db + rpb[h * 9 + ka];       // K-branch bias (incl. rpb)
            w[10] = db;                         // V-branch bias
            w[11] = 0.f;
        }
        return;
    }
    const float* src; ushort_t* dst; int off;
    if (idx < 12288) { src = wq; dst = wq16; off = idx * 4; }
    else             { src = wp; dst = wp16; off = (idx - 12288) * 4; }
    float4 v = *(const float4*)(src + off);
    uint2 st = { pk(v.x, v.y), pk(v.z, v.w) };
    *(uint2*)(dst + off) = st;
}

// ---------------------------------------------------------------------------
// qkv: f = x @ qkv_w^T + b via bf16 MFMA, f bf16 [b][o][pos].
// Mtile=64, Ntile=96, full K=256. Staging 100% global_load_lds w/ XOR swizzle
// (rows 512B bank-aligned; chunk q stored at q^(row&7)). LDS 80KB = 2 blk/CU.
// grid (49, 2, 16), 256 thr.
// ---------------------------------------------------------------------------
__global__ __launch_bounds__(256) void qkv_mfma(const ushort_t* __restrict__ xT,
                                                const ushort_t* __restrict__ wq16,
                                                const float* __restrict__ bias,
                                                ushort_t* __restrict__ f16) {
    __shared__ __align__(16) ushort_t wa[64 * 256];
    __shared__ __align__(16) ushort_t wb[96 * 256];
    const int tid = threadIdx.x;
    const int p0 = blockIdx.x * 64, o0 = blockIdx.y * 96, b = blockIdx.z;

    const ushort_t* xb = xT + ((size_t)(b * POS + p0)) * 256;
    #pragma unroll
    for (int it = 0; it < 8; ++it) {        // A: 64 rows x 32 chunks
        int idx = it * 256 + tid;
        int p = idx >> 5, q = idx & 31, qs = q ^ (p & 7);
        gll16(xb + (size_t)p * 256 + qs * 8, &wa[idx * 8]);
    }
    #pragma unroll
    for (int it = 0; it < 12; ++it) {       // B: 96 rows x 32 chunks
        int idx = it * 256 + tid;
        int n = idx >> 5, q = idx & 31, qs = q ^ (n & 7);
        gll16(wq16 + (size_t)(o0 + n) * 256 + qs * 8, &wb[idx * 8]);
    }
    __syncthreads();

    const int lane = tid & 63;
    const int wid  = tid >> 6;
    const int m0   = wid * 16;
    const int ml   = lane & 15;
    const int kg   = lane >> 4;

    f32x4 acc[6];
    #pragma unroll
    for (int u = 0; u < 6; ++u) acc[u] = (f32x4){0.f, 0.f, 0.f, 0.f};

    #pragma unroll
    for (int ks = 0; ks < 8; ++ks) {
        const int pj = ((ks * 4 + kg) ^ (ml & 7)) * 8;   // swizzled chunk (m&7==n&7==ml&7)
        bf16x8 af = *(const bf16x8*)&wa[(m0 + ml) * 256 + pj];
        #pragma unroll
        for (int u = 0; u < 6; ++u) {
            bf16x8 bf = *(const bf16x8*)&wb[(u * 16 + ml) * 256 + pj];
            acc[u] = __builtin_amdgcn_mfma_f32_16x16x32_bf16(af, bf, acc[u], 0, 0, 0);
        }
    }

    #pragma unroll
    for (int u = 0; u < 6; ++u) {
        int o = o0 + u * 16 + ml;
        float bj = bias[o];
        uint2 st = { pk(acc[u][0] + bj, acc[u][1] + bj),
                     pk(acc[u][2] + bj, acc[u][3] + bj) };
        *(uint2*)(f16 + ((size_t)b * QKVC + o) * POS + p0 + m0 + kg * 4) = st;
    }
}

// ---------------------------------------------------------------------------
// attn: R7-proven body; weights now read from GLOBAL with wave-uniform
// addresses -> compiler promotes to s_load into SGPRs (scalar/K$ pipe).
// Removes 432 broadcast ds_read_b128 per thread (was the saturated LDS pipe:
// ~147k LDS cycles/CU ~= the whole 65us kernel). LDS now only k/v halo tiles.
// grid (7, 8, 16), 448 thr.
// ---------------------------------------------------------------------------
#define TBH 8
__global__ __launch_bounds__(448) void attn_kernel(const ushort_t* __restrict__ f16,
                                                   const float* __restrict__ wattn,
                                                   float* __restrict__ aout) {
    __shared__ float kbuf[CH][TBH + 2][WW + 2];
    __shared__ float vbuf[CH][TBH + 2][WW + 2];

    const int tid = threadIdx.x;
    const int ty0 = blockIdx.x * TBH;
    const int h   = blockIdx.y;
    const int b   = blockIdx.z;
    const ushort_t* fb = f16 + ((size_t)b * QKVC + h * 24) * POS;

    const int HALO = (TBH + 2) * (WW + 2);   // 580
    for (int idx = tid; idx < 16 * HALO; idx += 448) {
        int c16 = idx / HALO;
        int rem = idx - c16 * HALO;
        int row = rem / (WW + 2);
        int col = rem - row * (WW + 2);
        int gy = ty0 + row - 1;
        int gx = col - 1;
        float val = 0.f;
        if (gy >= 0 && gy < HH && gx >= 0 && gx < WW) {
            int ch = c16 & 7;
            int o  = (c16 < 8) ? (8 + ch) : (16 + ch);
            val = bu2f(fb[o * POS + gy * WW + gx]);
        }
        float* dst = (c16 < 8) ? &kbuf[c16 & 7][0][0] : &vbuf[c16 & 7][0][0];
        dst[rem] = val;
    }
    __syncthreads();

    const int ly  = tid / WW;
    const int lx  = tid - ly * WW;
    const int pos = (ty0 + ly) * WW + lx;

    // per-head fused weight base: uniform across the block -> scalar loads
    const float4* wh = (const float4*)wattn + (size_t)h * 8 * 27;

    float q[CH];
    #pragma unroll
    for (int ch = 0; ch < CH; ++ch) q[ch] = bu2f(fb[ch * POS + pos]) * SCALE;

    float logits[9];
    #pragma unroll
    for (int ka = 0; ka < 9; ++ka) logits[ka] = 0.f;
    #pragma unroll
    for (int ch = 0; ch < CH; ++ch) {
        float n[9];
        #pragma unroll
        for (int dy = 0; dy < 3; ++dy)
            #pragma unroll
            for (int dx = 0; dx < 3; ++dx)
                n[dy * 3 + dx] = kbuf[ch][ly + dy][lx + dx];
        float qc = q[ch];
        const float4* wp = wh + ch * 27;
        #pragma unroll
        for (int ka = 0; ka < 9; ++ka) {
            float4 a4 = wp[ka * 3 + 0];
            float4 b4 = wp[ka * 3 + 1];
            float4 c4 = wp[ka * 3 + 2];
            float kv = n[ka] + c4.y;
            kv += n[0]*a4.x + n[1]*a4.y + n[2]*a4.z + n[3]*a4.w;
            kv += n[4]*b4.x + n[5]*b4.y + n[6]*b4.z + n[7]*b4.w;
            kv += n[8]*c4.x;
            logits[ka] += qc * kv;
        }
    }

    float m = logits[0];
    #pragma unroll
    for (int ka = 1; ka < 9; ++ka) m = fmaxf(m, logits[ka]);
    float att[9];
    float s = 0.f;
    #pragma unroll
    for (int ka = 0; ka < 9; ++ka) { att[ka] = __expf(logits[ka] - m); s += att[ka]; }
    float inv = 1.f / s;
    #pragma unroll
    for (int ka = 0; ka < 9; ++ka) att[ka] *= inv;

    float outv[CH];
    #pragma unroll
    for (int ch = 0; ch < CH; ++ch) {
        float n[9];
        #pragma unroll
        for (int dy = 0; dy < 3; ++dy)
            #pragma unroll
            for (int dx = 0; dx < 3; ++dx)
                n[dy * 3 + dx] = vbuf[ch][ly + dy][lx + dx];
        const float4* wp = wh + ch * 27;
        float o = 0.f;
        #pragma unroll
        for (int ka = 0; ka < 9; ++ka) {
            float4 a4 = wp[ka * 3 + 0];
            float4 b4 = wp[ka * 3 + 1];
            float4 c4 = wp[ka * 3 + 2];
            float vv = n[ka] + c4.z;
            vv += n[0]*a4.x + n[1]*a4.y + n[2]*a4.z + n[3]*a4.w;
            vv += n[4]*b4.x + n[5]*b4.y + n[6]*b4.z + n[7]*b4.w;
            vv += n[8]*c4.x;
            o += att[ka] * vv;
        }
        outv[ch] = o;
    }

    float* ap = aout + ((size_t)b * OC + h * CH) * POS + pos;
    #pragma unroll
    for (int ch = 0; ch < CH; ++ch) ap[ch * POS] = outv[ch];
}

// ---------------------------------------------------------------------------
// proj: out = a @ proj_w^T + b. A: coalesced fp32 -> LDS -> bf16 transpose.
// B: global_load_lds of pre-converted wp16 (swizzled). Mtile=64, Ntile=128.
// LDS ~42KB = 3 blk/CU. grid (49, 2, 16), 256 thr.
// ---------------------------------------------------------------------------
__global__ __launch_bounds__(256) void proj_mfma(const float* __restrict__ a,
                                                 const ushort_t* __restrict__ wp16,
                                                 const float* __restrict__ bias,
                                                 float* __restrict__ out) {
    __shared__ float ld[64][65];
    __shared__ __align__(16) ushort_t wa[64 * 72];
    __shared__ __align__(16) ushort_t wb[128 * 64];
    const int tid = threadIdx.x;
    const int p0 = blockIdx.x * 64, o0 = blockIdx.y * 128, b = blockIdx.z;

    // B: async GLL (rows 128B = 8 chunks, swizzled)
    #pragma unroll
    for (int it = 0; it < 4; ++it) {
        int idx = it * 256 + tid;
        int n = idx >> 3, q = idx & 7, qs = q ^ (n & 7);
        gll16(wp16 + (size_t)(o0 + n) * 64 + qs * 8, &wb[idx * 8]);
    }
    // A: coalesced fp32 tile
    const float* ab = a + (size_t)b * OC * POS + p0;
    #pragma unroll
    for (int it = 0; it < 4; ++it) {
        int idx = it * 256 + tid;
        int c = idx >> 4, pc = (idx & 15) << 2;
        float4 v = *(const float4*)(ab + (size_t)c * POS + pc);
        ld[c][pc] = v.x; ld[c][pc+1] = v.y; ld[c][pc+2] = v.z; ld[c][pc+3] = v.w;
    }
    __syncthreads();
    // pack transpose: wa[p][ch] stride 72
    #pragma unroll
    for (int it = 0; it < 2; ++it) {
        int idx = it * 256 + tid;
        int p = idx >> 3, q = (idx & 7) * 8;
        uint4 st = { pk(ld[q][p],   ld[q+1][p]), pk(ld[q+2][p], ld[q+3][p]),
                     pk(ld[q+4][p], ld[q+5][p]), pk(ld[q+6][p], ld[q+7][p]) };
        *(uint4*)&wa[p * 72 + q] = st;
    }
    __syncthreads();

    const int lane = tid & 63;
    const int wid  = tid >> 6;
    const int m0   = wid * 16;
    const int ml   = lane & 15;
    const int kg   = lane >> 4;

    f32x4 acc[8];
    #pragma unroll
    for (int u = 0; u < 8; ++u) acc[u] = (f32x4){0.f, 0.f, 0.f, 0.f};

    #pragma unroll
    for (int s = 0; s < 2; ++s) {
        bf16x8 af = *(const bf16x8*)&wa[(m0 + ml) * 72 + s * 32 + kg * 8];
        const int pj = ((s * 4 + kg) ^ (ml & 7)) * 8;
        #pragma unroll
        for (int u = 0; u < 8; ++u) {
            bf16x8 bf = *(const bf16x8*)&wb[(u * 16 + ml) * 64 + pj];
            acc[u] = __builtin_amdgcn_mfma_f32_16x16x32_bf16(af, bf, acc[u], 0, 0, 0);
        }
    }

    #pragma unroll
    for (int u = 0; u < 8; ++u) {
        int o = o0 + u * 16 + ml;
        float bj = bias[o];
        float4 st = { acc[u][0] + bj, acc[u][1] + bj, acc[u][2] + bj, acc[u][3] + bj };
        *(float4*)(out + ((size_t)b * 256 + o) * POS + p0 + m0 + kg * 4) = st;
    }
}

// ---------------------------------------------------------------------------
extern "C" void kernel_launch(void* const* d_in, const int* in_sizes, int n_in,
                              void* d_out, int out_size, void* d_ws, size_t ws_size,
                              hipStream_t stream) {
    const float* x      = (const float*)d_in[0];
    const float* qkv_w  = (const float*)d_in[1];
    const float* qkv_b  = (const float*)d_in[2];
    const float* dc_b   = (const float*)d_in[3];
    const float* dc1_w  = (const float*)d_in[4];
    const float* dc1_b  = (const float*)d_in[5];
    const float* rpb    = (const float*)d_in[6];
    const float* proj_w = (const float*)d_in[7];
    const float* proj_b = (const float*)d_in[8];
    float* out = (float*)d_out;

    // ws layout (45.1 MB base):
    //   f16   bf16 16*192*3136 = 19.27 MB
    //   xT    bf16 16*3136*256 = 25.69 MB  (dead after qkv; 'a' aliases it)
    //   wq16  96 KB, wp16 32 KB
    //   wattn 27 KB (fused attn weights) -- falls back to d_out scratch if
    //   ws is exactly-sized (d_out fully overwritten by proj afterwards).
    ushort_t* f16  = (ushort_t*)d_ws;
    ushort_t* xT   = f16 + (size_t)BATCH * QKVC * POS;
    ushort_t* wq16 = xT + (size_t)BATCH * POS * 256;
    ushort_t* wp16 = wq16 + 192 * 256;
    float*    a    = (float*)xT;            // alias: xT dead before attn writes

    const size_t WS_BASE = 45088768;        // bytes used by the four bufs above
    float* wattn = (ws_size >= WS_BASE + 6912 * sizeof(float))
                 ? (float*)((char*)d_ws + WS_BASE)
                 : (float*)d_out;           // scratch; proj rewrites all of out

    prep_x   <<<dim3(49, 4, BATCH), 256, 0, stream>>>(x, xT);
    prep_w   <<<dim3(67),           256, 0, stream>>>(qkv_w, proj_w, dc_b, dc1_w,
                                                      dc1_b, rpb, wq16, wp16, wattn);
    qkv_mfma <<<dim3(49, 2, BATCH), 256, 0, stream>>>(xT, wq16, qkv_b, f16);
    attn_kernel<<<dim3(7, NH, BATCH), 448, 0, stream>>>(f16, wattn, a);
    proj_mfma<<<dim3(49, 2, BATCH), 256, 0, stream>>>(a, wp16, proj_b, out);
}